// Round 15
// baseline (100.744 us; speedup 1.0000x reference)
//
#include <hip/hip_runtime.h>
#include <hip/hip_bf16.h>

#define EPSW 1e-6f

typedef __attribute__((ext_vector_type(4))) float floatx4;
typedef __attribute__((ext_vector_type(8))) short shortx8;   // 8 bf16 (4 VGPRs)

// round-to-nearest-even float -> bf16 bits (finite inputs)
__device__ __forceinline__ unsigned short f2bf(float f) {
    unsigned int u = __float_as_uint(f);
    u = (u + 0x7fffu + ((u >> 16) & 1u)) >> 16;
    return (unsigned short)u;
}

// async global->LDS DMA, 16B per lane: lane i's 16B land at l + i*16.
// lds base must be wave-uniform (m104/m108).
__device__ __forceinline__ void gl_lds16(const void* g, void* l) {
    __builtin_amdgcn_global_load_lds(
        (const __attribute__((address_space(1))) unsigned int*)g,
        (__attribute__((address_space(3))) unsigned int*)l, 16, 0, 0);
}

// ---------------------------------------------------------------------------
// prep: 273 blocks x 512 threads (r13-validated, unchanged).
//   blocks 0..255 : xt transpose. x (2048x2000 fp32) -> xt bf16, granule
//                   (kg,row) at linear index kg*2048+row (16B granules),
//                   K padded to 2048. Block = 64 rows x 32 kg.
//   blocks 256..271: W -> wt bf16, granule (kg,h) at kg*128+h, zero-padded.
//   block 272     : A (normalized adjacency) + Mt[c][n] = (A@A)[n][c].
// ---------------------------------------------------------------------------
__global__ __launch_bounds__(512) void prep(const float* __restrict__ x,
                                            const float* __restrict__ W,
                                            const int* __restrict__ ei,
                                            const float* __restrict__ ew,
                                            unsigned short* __restrict__ xt,
                                            unsigned short* __restrict__ wt,
                                            float* __restrict__ Mt) {
    __shared__ __align__(16) unsigned char smem[64 * 264 * 2];  // 33792 B
    const int bid = blockIdx.x;
    const int t   = threadIdx.x;

    if (bid < 256) {
        unsigned short(*tile)[264] = (unsigned short(*)[264])smem;  // +8 pad
        const int rb   = (bid >> 3) * 64;      // 32 row-tiles
        const int kgb  = (bid & 7) * 32;       // 8 kg-tiles
        const int kbas = kgb * 8;
#pragma unroll
        for (int i = 0; i < 8; ++i) {
            const int idx = i * 512 + t;
            const int r   = idx >> 6;          // 0..63
            const int kc  = (idx & 63) * 4;    // 0..252
            const int k   = kbas + kc;
            floatx4 v = (floatx4){0.f, 0.f, 0.f, 0.f};
            if (k < 2000)
                v = *(const floatx4*)(x + (size_t)(rb + r) * 2000 + k);
            tile[r][kc + 0] = f2bf(v.x);
            tile[r][kc + 1] = f2bf(v.y);
            tile[r][kc + 2] = f2bf(v.z);
            tile[r][kc + 3] = f2bf(v.w);
        }
        __syncthreads();
#pragma unroll
        for (int i = 0; i < 4; ++i) {
            const int kg_l = i * 8 + (t >> 6);  // wave-uniform, 0..31
            const int r    = t & 63;
            const shortx8 g = *(const shortx8*)&tile[r][kg_l * 8];
            *(shortx8*)(xt + ((size_t)(kgb + kg_l) * 2048 + rb + r) * 8) = g;
        }
    } else if (bid < 272) {
#pragma unroll
        for (int i = 0; i < 4; ++i) {
            const int G  = (bid - 256) * 2048 + i * 512 + t;  // 0..32767
            const int kg = G >> 7;
            const int h  = G & 127;
            const int k  = kg * 8;
            floatx4 v0 = (floatx4){0.f, 0.f, 0.f, 0.f};
            floatx4 v1 = (floatx4){0.f, 0.f, 0.f, 0.f};
            if (k < 2000) {  // kg<=249 -> whole granule valid
                v0 = *(const floatx4*)(W + (size_t)h * 2000 + k);
                v1 = *(const floatx4*)(W + (size_t)h * 2000 + k + 4);
            }
            unsigned short* p = wt + ((size_t)kg * 128 + h) * 8;
            p[0] = f2bf(v0.x); p[1] = f2bf(v0.y); p[2] = f2bf(v0.z); p[3] = f2bf(v0.w);
            p[4] = f2bf(v1.x); p[5] = f2bf(v1.y); p[6] = f2bf(v1.z); p[7] = f2bf(v1.w);
        }
    } else {
        float* A    = (float*)smem;            // 4096 f
        float* deg  = (float*)(smem + 16384);
        float* dinv = deg + 64;
        if (t < 64) deg[t] = 1.0f;             // self-loop pre-added
        for (int i = t; i < 4096; i += 512) A[i] = 0.0f;
        __syncthreads();
        const int* srcp = ei;
        const int* dstp = ei + 4096;
#pragma unroll
        for (int i = 0; i < 8; ++i) {
            const int e = i * 512 + t;
            float w = ew[e];
            w = (w <= 0.0f) ? EPSW : w;
            atomicAdd(&deg[dstp[e]], w);
        }
        __syncthreads();
        if (t < 64) dinv[t] = 1.0f / sqrtf(deg[t]);
        __syncthreads();
#pragma unroll
        for (int i = 0; i < 8; ++i) {
            const int e = i * 512 + t;
            float w = ew[e];
            w = (w <= 0.0f) ? EPSW : w;
            const int s = srcp[e], d = dstp[e];
            atomicAdd(&A[d * 64 + s], dinv[s] * w * dinv[d]);
        }
        if (t < 64) atomicAdd(&A[t * 64 + t], dinv[t] * dinv[t]);
        __syncthreads();
#pragma unroll
        for (int i = 0; i < 8; ++i) {
            const int idx = i * 512 + t;
            const int n = idx >> 6, c = idx & 63;
            float s = 0.0f;
#pragma unroll 8
            for (int k = 0; k < 64; ++k) s += A[n * 64 + k] * A[k * 64 + c];
            Mt[c * 64 + n] = s;
        }
    }
}

// ---------------------------------------------------------------------------
// gemm_dma_apply: 256 blocks x 512 threads (8 waves). Block bid = ht*32 + b
// (b = batch, ht = 16-h tile; bid%8 == b%8 -> XCD pinning: 4 batches/XCD,
// xt slice 256 KB/batch + wt 512 KB -> L2-resident re-reads).
// Full K=2048 in-block: 32 chunks of BK=64 (8 kg), double-buffered, staged
// by exactly 10 global_load_lds width-16 per chunk:
//   A: wave j (j=0..7) issues ONE DMA -> xbuf[kgl=j][row 0..63] (16B/row).
//      (r14 BUG fixed: previously each wave issued a second DMA at
//      (wave+4)*1024 which overflowed the 8 KB buffer for waves 4..7.)
//   B: waves 0..1 issue one DMA each -> wbuf[kgl=wave*4+(lane>>4)][hl].
// Wave (rt 0..3, kh 0..1): 1 MFMA per chunk (kgl = kh*4+q), acc parity
// alternates per chunk. Per-wave s_waitcnt(0) + barrier publishes DMA.
// Epilogue (in-block, r5-validated): kh-reduce via zs[64][17], then
// y = M.z + bias with Ms staged from Mt at kernel start.
// ---------------------------------------------------------------------------
__global__ __launch_bounds__(512) void gemm_dma_apply(
        const unsigned short* __restrict__ xt,
        const unsigned short* __restrict__ wt,
        const float* __restrict__ Mt,
        const float* __restrict__ bias,
        float* __restrict__ y) {
    __shared__ __align__(16) unsigned char xbuf[2][8192];   // 8 kg x 64 rows x 16B
    __shared__ __align__(16) unsigned char wbuf[2][2048];   // 8 kg x 16 h x 16B
    __shared__ float Ms[4096];
    __shared__ float zs[64][17];
    const int t    = threadIdx.x;
    const int wave = t >> 6, lane = t & 63;
    const int m = lane & 15, q = lane >> 4;
    const int bid = blockIdx.x;
    const int b   = bid & 31;
    const int ht  = bid >> 5;
    const int rt = wave & 3, kh = wave >> 2;
    const int rbase = b * 64;

    // stage Ms from global (completes under the K-loop)
    {
        const floatx4* Mg4 = (const floatx4*)Mt;
        floatx4* Ms4 = (floatx4*)Ms;
        Ms4[t]       = Mg4[t];
        Ms4[t + 512] = Mg4[t + 512];
    }

#define ISSUE_CHUNK(c)                                                        \
    {                                                                         \
        const int ckg = (c) * 8;                                              \
        unsigned char* xb = xbuf[(c) & 1];                                    \
        unsigned char* wb = wbuf[(c) & 1];                                    \
        gl_lds16(xt + ((size_t)(ckg + wave) * 2048 + rbase + lane) * 8,       \
                 xb + wave * 1024);                                           \
        if (wave < 2)                                                         \
            gl_lds16(wt + ((size_t)(ckg + wave * 4 + (lane >> 4)) * 128 +     \
                           ht * 16 + (lane & 15)) * 8,                        \
                     wb + wave * 1024);                                       \
    }

    floatx4 acc0 = (floatx4){0.f, 0.f, 0.f, 0.f};
    floatx4 acc1 = (floatx4){0.f, 0.f, 0.f, 0.f};

    ISSUE_CHUNK(0);
    for (int c = 0; c < 32; ++c) {
        __builtin_amdgcn_s_waitcnt(0);   // own DMA drained
        __syncthreads();                 // all waves' DMA published
        if (c < 31) ISSUE_CHUNK(c + 1);  // async into other buffer
        const unsigned char* xb = xbuf[c & 1];
        const unsigned char* wb = wbuf[c & 1];
        const int kgl = kh * 4 + q;
        const shortx8 af = *(const shortx8*)(xb + kgl * 1024 + (rt * 16 + m) * 16);
        const shortx8 bf = *(const shortx8*)(wb + kgl * 256 + m * 16);
        if (c & 1) acc1 = __builtin_amdgcn_mfma_f32_16x16x32_bf16(af, bf, acc1, 0, 0, 0);
        else       acc0 = __builtin_amdgcn_mfma_f32_16x16x32_bf16(af, bf, acc0, 0, 0, 0);
        __syncthreads();                 // reads done before buffer reuse
    }
    acc0 += acc1;

    // ===== kh-reduce + apply M + bias (r5-validated) =====
    // C/D layout: row = q*4+v, col = m. zs padded [64][17].
    if (kh == 0) {
#pragma unroll
        for (int v = 0; v < 4; ++v) zs[rt * 16 + q * 4 + v][m] = acc0[v];
    }
    __syncthreads();
    if (kh == 1) {
#pragma unroll
        for (int v = 0; v < 4; ++v) zs[rt * 16 + q * 4 + v][m] += acc0[v];
    }
    __syncthreads();
    {
        const int n0 = t >> 4;        // 0..31
        const int h  = t & 15;
        const float bv = bias[ht * 16 + h];
        float s0 = bv, s1 = bv;
#pragma unroll
        for (int mm = 0; mm < 64; ++mm) {
            const float zv = zs[mm][h];                 // 16-lane broadcast
            s0 += Ms[mm * 64 + n0]      * zv;           // 4 banks x broadcast
            s1 += Ms[mm * 64 + n0 + 32] * zv;
        }
        float* yp = y + (size_t)b * 8192 + ht * 16 + h;
        yp[(size_t)n0 * 128]        = s0;
        yp[(size_t)(n0 + 32) * 128] = s1;
    }
}

extern "C" void kernel_launch(void* const* d_in, const int* in_sizes, int n_in,
                              void* d_out, int out_size, void* d_ws, size_t ws_size,
                              hipStream_t stream) {
    const float* x    = (const float*)d_in[0];   // (2048, 2000) fp32
    const int*   ei   = (const int*)d_in[1];     // (2, 4096)
    const float* ew   = (const float*)d_in[2];   // (4096,)
    const float* W    = (const float*)d_in[3];   // (128, 2000) fp32
    const float* bias = (const float*)d_in[4];   // (128,)
    float* y = (float*)d_out;                    // (32, 64, 128) fp32

    float* Mt = (float*)d_ws;                            // 4096 f
    unsigned short* xt = (unsigned short*)(Mt + 4096);   // 256*2048*8 bf16 (8 MB)
    unsigned short* wt = xt + 4194304;                   // 256*128*8 bf16 (512 KB)

    prep<<<273, 512, 0, stream>>>(x, W, ei, ew, xt, wt, Mt);
    gemm_dma_apply<<<256, 512, 0, stream>>>(xt, wt, Mt, bias, y);
}

// Round 16
// 96.503 us; speedup vs baseline: 1.0439x; 1.0439x over previous
//
#include <hip/hip_runtime.h>
#include <hip/hip_bf16.h>

#define EPSW 1e-6f

typedef __attribute__((ext_vector_type(4))) float floatx4;
typedef __attribute__((ext_vector_type(8))) short shortx8;   // 8 bf16 (4 VGPRs)

// round-to-nearest-even float -> bf16 bits (finite inputs)
__device__ __forceinline__ unsigned short f2bf(float f) {
    unsigned int u = __float_as_uint(f);
    u = (u + 0x7fffu + ((u >> 16) & 1u)) >> 16;
    return (unsigned short)u;
}

// async global->LDS DMA, 16B per lane: lane i's 16B land at l + i*16.
__device__ __forceinline__ void gl_lds16(const void* g, void* l) {
    __builtin_amdgcn_global_load_lds(
        (const __attribute__((address_space(1))) unsigned int*)g,
        (__attribute__((address_space(3))) unsigned int*)l, 16, 0, 0);
}

// ---------------------------------------------------------------------------
// prep: 273 blocks x 512 threads (r13-validated).
//   blocks 0..255 : xt transpose. x (2048x2000 fp32) -> xt bf16, granule
//                   (kg,row) linear at index kg*2048+row (16B granules),
//                   K padded to 2048. Block = 64 rows x 32 kg.
//   blocks 256..271: W -> wt bf16, granule (kg,h) at kg*128+h, zero-padded.
//   block 272     : A (normalized adjacency) + Mt[c][n] = (A@A)[n][c].
// ---------------------------------------------------------------------------
__global__ __launch_bounds__(512) void prep(const float* __restrict__ x,
                                            const float* __restrict__ W,
                                            const int* __restrict__ ei,
                                            const float* __restrict__ ew,
                                            unsigned short* __restrict__ xt,
                                            unsigned short* __restrict__ wt,
                                            float* __restrict__ Mt) {
    __shared__ __align__(16) unsigned char smem[64 * 264 * 2];  // 33792 B
    const int bid = blockIdx.x;
    const int t   = threadIdx.x;

    if (bid < 256) {
        unsigned short(*tile)[264] = (unsigned short(*)[264])smem;  // +8 pad
        const int rb   = (bid >> 3) * 64;      // 32 row-tiles
        const int kgb  = (bid & 7) * 32;       // 8 kg-tiles
        const int kbas = kgb * 8;
#pragma unroll
        for (int i = 0; i < 8; ++i) {
            const int idx = i * 512 + t;
            const int r   = idx >> 6;          // 0..63
            const int kc  = (idx & 63) * 4;    // 0..252
            const int k   = kbas + kc;
            floatx4 v = (floatx4){0.f, 0.f, 0.f, 0.f};
            if (k < 2000)
                v = *(const floatx4*)(x + (size_t)(rb + r) * 2000 + k);
            tile[r][kc + 0] = f2bf(v.x);
            tile[r][kc + 1] = f2bf(v.y);
            tile[r][kc + 2] = f2bf(v.z);
            tile[r][kc + 3] = f2bf(v.w);
        }
        __syncthreads();
#pragma unroll
        for (int i = 0; i < 4; ++i) {
            const int kg_l = i * 8 + (t >> 6);  // wave-uniform, 0..31
            const int r    = t & 63;
            const shortx8 g = *(const shortx8*)&tile[r][kg_l * 8];
            *(shortx8*)(xt + ((size_t)(kgb + kg_l) * 2048 + rb + r) * 8) = g;
        }
    } else if (bid < 272) {
#pragma unroll
        for (int i = 0; i < 4; ++i) {
            const int G  = (bid - 256) * 2048 + i * 512 + t;  // 0..32767
            const int kg = G >> 7;
            const int h  = G & 127;
            const int k  = kg * 8;
            floatx4 v0 = (floatx4){0.f, 0.f, 0.f, 0.f};
            floatx4 v1 = (floatx4){0.f, 0.f, 0.f, 0.f};
            if (k < 2000) {  // kg<=249 -> whole granule valid
                v0 = *(const floatx4*)(W + (size_t)h * 2000 + k);
                v1 = *(const floatx4*)(W + (size_t)h * 2000 + k + 4);
            }
            unsigned short* p = wt + ((size_t)kg * 128 + h) * 8;
            p[0] = f2bf(v0.x); p[1] = f2bf(v0.y); p[2] = f2bf(v0.z); p[3] = f2bf(v0.w);
            p[4] = f2bf(v1.x); p[5] = f2bf(v1.y); p[6] = f2bf(v1.z); p[7] = f2bf(v1.w);
        }
    } else {
        float* A    = (float*)smem;            // 4096 f
        float* deg  = (float*)(smem + 16384);
        float* dinv = deg + 64;
        if (t < 64) deg[t] = 1.0f;             // self-loop pre-added
        for (int i = t; i < 4096; i += 512) A[i] = 0.0f;
        __syncthreads();
        const int* srcp = ei;
        const int* dstp = ei + 4096;
#pragma unroll
        for (int i = 0; i < 8; ++i) {
            const int e = i * 512 + t;
            float w = ew[e];
            w = (w <= 0.0f) ? EPSW : w;
            atomicAdd(&deg[dstp[e]], w);
        }
        __syncthreads();
        if (t < 64) dinv[t] = 1.0f / sqrtf(deg[t]);
        __syncthreads();
#pragma unroll
        for (int i = 0; i < 8; ++i) {
            const int e = i * 512 + t;
            float w = ew[e];
            w = (w <= 0.0f) ? EPSW : w;
            const int s = srcp[e], d = dstp[e];
            atomicAdd(&A[d * 64 + s], dinv[s] * w * dinv[d]);
        }
        if (t < 64) atomicAdd(&A[t * 64 + t], dinv[t] * dinv[t]);
        __syncthreads();
#pragma unroll
        for (int i = 0; i < 8; ++i) {
            const int idx = i * 512 + t;
            const int n = idx >> 6, c = idx & 63;
            float s = 0.0f;
#pragma unroll 8
            for (int k = 0; k < 64; ++k) s += A[n * 64 + k] * A[k * 64 + c];
            Mt[c * 64 + n] = s;
        }
    }
}

// ---------------------------------------------------------------------------
// gemm_lds: m97-style async-DMA GEMM (r13-measured best). 256 blocks x 256
// threads (4 waves). Block bid: ks = bid>>5 (K-slice of 256 = 32 kg),
// rbase = (bid&31)*64.
// K-loop: 4 chunks of BK=64 (8 kg), double-buffered. Each chunk staged by 24
// global_load_lds width-16 instructions (A: 8 x [64 rows], B: 16 x [64 h]),
// spread over the 4 waves -- async DMA, no VGPR round-trip, overlaps with
// the previous chunk's ds_read+MFMA.
// LDS per buf: A 8 kg x 64 rows x 16B = 8 KB | B 8 kg x 128 h x 16B = 16 KB.
// Compute: wave w owns h-tiles {w, w+4}: acc[rt 0..3][hh 0..1]; per chunk
// 2 k-quads x (4 A + 2 B ds_read_b128, 8 MFMA) = 16 MFMA.
// Epilogue: partials to zp[ks][row][h] (unique owner, plain stores).
// ---------------------------------------------------------------------------
__global__ __launch_bounds__(256) void gemm_lds(
        const unsigned short* __restrict__ xt,
        const unsigned short* __restrict__ wt,
        float* __restrict__ zp) {
    __shared__ __align__(16) unsigned char smem[2][24576];
    const int t    = threadIdx.x;
    const int wave = t >> 6, lane = t & 63;
    const int m = lane & 15, q = lane >> 4;
    const int bid   = blockIdx.x;
    const int ks    = bid >> 5;         // 0..7
    const int rbase = (bid & 31) * 64;  // 0..1984
    const int kg0   = ks * 32;

    floatx4 acc[4][2];
#pragma unroll
    for (int rt = 0; rt < 4; ++rt)
#pragma unroll
        for (int hh = 0; hh < 2; ++hh)
            acc[rt][hh] = (floatx4){0.f, 0.f, 0.f, 0.f};

    // issue DMA for chunk c into smem[c&1]
#define ISSUE_CHUNK(c)                                                        \
    {                                                                         \
        unsigned char* sb = smem[(c) & 1];                                    \
        const int ckg = kg0 + (c) * 8;                                        \
        for (int j = wave; j < 24; j += 4) {                                  \
            if (j < 8) {                                                      \
                gl_lds16(xt + ((size_t)(ckg + j) * 2048 + rbase + lane) * 8,  \
                         sb + j * 1024);                                      \
            } else {                                                          \
                const int kgl = (j - 8) >> 1, hf = (j - 8) & 1;               \
                gl_lds16(wt + ((size_t)(ckg + kgl) * 128 + hf * 64 + lane) * 8,\
                         sb + 8192 + kgl * 2048 + hf * 1024);                 \
            }                                                                 \
        }                                                                     \
    }

    ISSUE_CHUNK(0);
    for (int c = 0; c < 4; ++c) {
        __builtin_amdgcn_s_waitcnt(0);   // own DMA drained
        __syncthreads();                 // all waves' DMA published
        if (c < 3) ISSUE_CHUNK(c + 1);   // async into other buffer
        const unsigned char* sb = smem[c & 1];
#pragma unroll
        for (int p = 0; p < 2; ++p) {
            // A-frags: granule (kgl = p*4+q, row = rt*16+m)
            shortx8 a[4];
#pragma unroll
            for (int rt = 0; rt < 4; ++rt)
                a[rt] = *(const shortx8*)(sb + (p * 4 + q) * 1024 + (rt * 16 + m) * 16);
            // B-frags: granule (kgl, h = (wave+hh*4)*16+m)
            shortx8 bb[2];
#pragma unroll
            for (int hh = 0; hh < 2; ++hh)
                bb[hh] = *(const shortx8*)(sb + 8192 + (p * 4 + q) * 2048 +
                                           ((wave + hh * 4) * 16 + m) * 16);
#pragma unroll
            for (int rt = 0; rt < 4; ++rt)
#pragma unroll
                for (int hh = 0; hh < 2; ++hh)
                    acc[rt][hh] = __builtin_amdgcn_mfma_f32_16x16x32_bf16(
                        a[rt], bb[hh], acc[rt][hh], 0, 0, 0);
        }
        __syncthreads();                 // all reads of buf c done before reuse
    }

    // epilogue: partial z. C/D layout: row = q*4+v, col = m.
#pragma unroll
    for (int rt = 0; rt < 4; ++rt)
#pragma unroll
        for (int hh = 0; hh < 2; ++hh) {
            const int h = (wave + hh * 4) * 16 + m;
#pragma unroll
            for (int v = 0; v < 4; ++v) {
                const int row = rbase + rt * 16 + q * 4 + v;
                zp[((size_t)ks * 2048 + row) * 128 + h] = acc[rt][hh][v];
            }
        }
}

// ---------------------------------------------------------------------------
// apply_M: y[b][n][h] = bias[h] + sum_m M[n][m] * (sum_ks zp[ks][b*64+m][h])
// Grid (32 b, 8 h-chunks of 16) x 256 thr (r13-validated).
// ---------------------------------------------------------------------------
__global__ __launch_bounds__(256) void apply_M(const float* __restrict__ zp,
                                               const float* __restrict__ Mtg,
                                               const float* __restrict__ bias,
                                               float* __restrict__ y) {
    __shared__ float Ms[4096];
    __shared__ float zs[64][16];
    const int b  = blockIdx.x;
    const int hc = blockIdx.y;
    const int t  = threadIdx.x;
#pragma unroll
    for (int i = 0; i < 16; ++i) Ms[i * 256 + t] = Mtg[i * 256 + t];
#pragma unroll
    for (int i = 0; i < 4; ++i) {
        const int idx = i * 256 + t;
        const int mr = idx >> 4, hh = idx & 15;
        float s = 0.0f;
#pragma unroll
        for (int ks = 0; ks < 8; ++ks)
            s += zp[((size_t)ks * 2048 + b * 64 + mr) * 128 + hc * 16 + hh];
        zs[mr][hh] = s;
    }
    __syncthreads();
    const int h  = t & 15;
    const int n0 = (t >> 4) * 4;
    const float bv = bias[hc * 16 + h];
    float s0 = bv, s1 = bv, s2 = bv, s3 = bv;
#pragma unroll
    for (int mm = 0; mm < 64; ++mm) {
        const float zv = zs[mm][h];
        s0 += Ms[mm * 64 + n0 + 0] * zv;
        s1 += Ms[mm * 64 + n0 + 1] * zv;
        s2 += Ms[mm * 64 + n0 + 2] * zv;
        s3 += Ms[mm * 64 + n0 + 3] * zv;
    }
    float* yp = y + (size_t)b * 8192 + (size_t)n0 * 128 + hc * 16 + h;
    yp[0]   = s0;
    yp[128] = s1;
    yp[256] = s2;
    yp[384] = s3;
}

extern "C" void kernel_launch(void* const* d_in, const int* in_sizes, int n_in,
                              void* d_out, int out_size, void* d_ws, size_t ws_size,
                              hipStream_t stream) {
    const float* x    = (const float*)d_in[0];   // (2048, 2000) fp32
    const int*   ei   = (const int*)d_in[1];     // (2, 4096)
    const float* ew   = (const float*)d_in[2];   // (4096,)
    const float* W    = (const float*)d_in[3];   // (128, 2000) fp32
    const float* bias = (const float*)d_in[4];   // (128,)
    float* y = (float*)d_out;                    // (32, 64, 128) fp32

    float* zp = (float*)d_ws;                            // 8*2048*128 f (8 MB)
    float* Mt = zp + 2097152;                            // 4096 f
    unsigned short* xt = (unsigned short*)(Mt + 4096);   // 256*2048*8 bf16 (8 MB)
    unsigned short* wt = xt + 4194304;                   // 256*128*8 bf16 (512 KB)

    prep<<<273, 512, 0, stream>>>(x, W, ei, ew, xt, wt, Mt);
    gemm_lds<<<256, 256, 0, stream>>>(xt, wt, zp);
    apply_M<<<dim3(32, 8), 256, 0, stream>>>(zp, Mt, bias, y);
}